// Round 10
// baseline (186.234 us; speedup 1.0000x reference)
//
#include <hip/hip_runtime.h>
#include <hip/hip_bf16.h>

// B=2, T=4096, D=512, H=8, HD=64
#define BB 2
#define TT 4096
#define DD 512
#define HH 8
#define HD 64
#define M_TOT (BB*TT)          // 8192
#define N_QKV (3*DD)           // 1536

typedef __attribute__((ext_vector_type(8))) __bf16 bf16x8;
typedef __attribute__((ext_vector_type(4))) float f32x4;

#define MFMA32(a,b,c) __builtin_amdgcn_mfma_f32_16x16x32_bf16((a),(b),(c),0,0,0)

// softmax with FIXED shift: p = exp(s/8 - 8) = exp2(s*SCALE_L2E - SHIFT_L2E)
#define SCALE_L2E 0.18033688011112443f   // 0.125 * log2(e)
#define SHIFT_L2E 11.541560327111707f    // 8 * log2(e)

// result = [lo16 = hi16(lo_u), hi16 = hi16(hi_u)]
static __device__ __forceinline__ unsigned pack_hi16(unsigned lo_u, unsigned hi_u) {
#if __has_builtin(__builtin_amdgcn_perm)
    return __builtin_amdgcn_perm(hi_u, lo_u, 0x07060302u);
#else
    return (lo_u >> 16) | (hi_u & 0xffff0000u);
#endif
}
// two fp32 -> packed bf16 pair, truncating (attn P path; bias cancels in softmax)
static __device__ __forceinline__ unsigned bfpack2_t(float a, float b) {
    union { float f; unsigned u; } x, y; x.f = a; y.f = b;
    return pack_hi16(x.u, y.u);
}
// two fp32 -> packed bf16 pair, round-half-up (GEMM staging)
static __device__ __forceinline__ unsigned bfpack2_r(float a, float b) {
    union { float f; unsigned u; } x, y; x.f = a; y.f = b;
    return pack_hi16(x.u + 0x8000u, y.u + 0x8000u);
}
static __device__ __forceinline__ unsigned short f2bf(float f) {
    union { float f; unsigned u; } v; v.f = f;
    return (unsigned short)((v.u + 0x8000u) >> 16);
}
static __device__ __forceinline__ unsigned short f2bf_t(float f) {
    union { float f; unsigned u; } v; v.f = f;
    return (unsigned short)(v.u >> 16);
}

static __device__ __forceinline__ bf16x8 load8(const unsigned short* p) {
    bf16x8 v;
    __builtin_memcpy(&v, p, 16);
    return v;
}

static __device__ __forceinline__ bf16x8 ones_frag() {
    unsigned short u[8];
    #pragma unroll
    for (int i = 0; i < 8; i++) u[i] = 0x3F80;   // bf16 1.0
    bf16x8 v; __builtin_memcpy(&v, u, 16);
    return v;
}

// pack 16 fp32 (4 float4) into 8 dwords of bf16
static __device__ __forceinline__ void pack16(const float4& a0, const float4& a1,
                                              const float4& a2, const float4& a3,
                                              unsigned* o) {
    o[0] = bfpack2_r(a0.x, a0.y); o[1] = bfpack2_r(a0.z, a0.w);
    o[2] = bfpack2_r(a1.x, a1.y); o[3] = bfpack2_r(a1.z, a1.w);
    o[4] = bfpack2_r(a2.x, a2.y); o[5] = bfpack2_r(a2.z, a2.w);
    o[6] = bfpack2_r(a3.x, a3.y); o[7] = bfpack2_r(a3.z, a3.w);
}

// ---------------- QKV GEMM: [8192,512]fp32 x [1536,512]^T fp32, fused cast ----------------
// register-path staging with rotational chunk swizzle (bank-floor reads+writes)
__global__ __launch_bounds__(256) void qkv_gemm(
        const float* __restrict__ x,
        const float* __restrict__ wqkv,
        unsigned short* __restrict__ qb,
        unsigned short* __restrict__ kb,
        unsigned short* __restrict__ vtb) {
    __shared__ union {
        struct { unsigned short As[128 * 32]; unsigned short Bs[128 * 32]; } g;
        unsigned short vt[4][64][72];   // per-wave V-transpose tile
    } sm;
    int tid = threadIdx.x;
    int w = tid >> 6, lane = tid & 63;
    int lrow = lane & 15, quad = lane >> 4;
    int bn = blockIdx.x % (N_QKV / 128);      // 12
    int bm = blockIdx.x / (N_QKV / 128);
    int m0 = bm * 128, n0 = bn * 128;
    int wm = w >> 1, wn = w & 1;
    int srow = tid >> 1, shalf = tid & 1;     // staging: row 0..127, 16-col half
    int srs = (srow >> 1) & 3;
    int sc0 = (2 * shalf + srs) & 3;          // swizzled chunk ids
    int sc1 = (2 * shalf + 1 + srs) & 3;
    int rs = (lrow >> 1) & 3;                 // fragment-read swizzle

    f32x4 c[4][4];
    #pragma unroll
    for (int i = 0; i < 4; i++)
        #pragma unroll
        for (int j = 0; j < 4; j++) c[i][j] = (f32x4){0.f, 0.f, 0.f, 0.f};

    for (int k0 = 0; k0 < DD; k0 += 32) {
        const float4* ax = (const float4*)(x + (size_t)(m0 + srow) * DD + k0 + shalf * 16);
        const float4* bx = (const float4*)(wqkv + (size_t)(n0 + srow) * DD + k0 + shalf * 16);
        float4 a0 = ax[0], a1 = ax[1], a2 = ax[2], a3 = ax[3];
        float4 b0 = bx[0], b1 = bx[1], b2 = bx[2], b3 = bx[3];
        unsigned ap[8], bp[8];
        pack16(a0, a1, a2, a3, ap);
        pack16(b0, b1, b2, b3, bp);
        __builtin_memcpy(&sm.g.As[srow * 32 + sc0 * 8], &ap[0], 16);
        __builtin_memcpy(&sm.g.As[srow * 32 + sc1 * 8], &ap[4], 16);
        __builtin_memcpy(&sm.g.Bs[srow * 32 + sc0 * 8], &bp[0], 16);
        __builtin_memcpy(&sm.g.Bs[srow * 32 + sc1 * 8], &bp[4], 16);
        __syncthreads();
        bf16x8 a[4], b[4];
        #pragma unroll
        for (int mf = 0; mf < 4; mf++)
            a[mf] = load8(&sm.g.As[(wm * 64 + mf * 16 + lrow) * 32 + ((quad + rs) & 3) * 8]);
        #pragma unroll
        for (int nf = 0; nf < 4; nf++)
            b[nf] = load8(&sm.g.Bs[(wn * 64 + nf * 16 + lrow) * 32 + ((quad + rs) & 3) * 8]);
        #pragma unroll
        for (int mf = 0; mf < 4; mf++)
            #pragma unroll
            for (int nf = 0; nf < 4; nf++)
                c[mf][nf] = MFMA32(a[mf], b[nf], c[mf][nf]);
        __syncthreads();
    }

    int m0w = m0 + wm * 64, n0w = n0 + wn * 64;
    int which = n0w >> 9;            // 0=q 1=k 2=v
    int h = (n0w & 511) >> 6;
    if (which < 2) {
        unsigned short* dst = (which == 0) ? qb : kb;
        #pragma unroll
        for (int mf = 0; mf < 4; mf++) {
            #pragma unroll
            for (int r = 0; r < 4; r++) {
                int m = m0w + mf * 16 + quad * 4 + r;
                int t = m & (TT - 1), bi = m >> 12;
                size_t hb = (size_t)(bi * HH + h) * TT + t;
                #pragma unroll
                for (int nf = 0; nf < 4; nf++)
                    dst[hb * HD + nf * 16 + lrow] = f2bf(c[mf][nf][r]);
            }
        }
    } else {
        #pragma unroll
        for (int mf = 0; mf < 4; mf++)
            #pragma unroll
            for (int r = 0; r < 4; r++)
                #pragma unroll
                for (int nf = 0; nf < 4; nf++)
                    sm.vt[w][nf * 16 + lrow][mf * 16 + quad * 4 + r] = f2bf(c[mf][nf][r]);
        int bi = m0w >> 12, t0 = m0w & (TT - 1);
        size_t hb = (size_t)(bi * HH + h) * HD;
        #pragma unroll
        for (int i = 0; i < 8; i++) {
            int d = i * 8 + (lane >> 3);
            int tc = (lane & 7) * 8;
            bf16x8 v;
            __builtin_memcpy(&v, &sm.vt[w][d][tc], 16);
            __builtin_memcpy(vtb + (hb + d) * TT + t0 + tc, &v, 16);
        }
    }
}

// ---------------- Flash attention (causal, fixed-shift softmax) ----------------
// Paired q-tiles (p, 63-p) = 65 kt-units/block; 4 waves, kt stride 4.
// S^T = MFMA(K,Q): lane holds 4 k-consecutive P values -> pack -> ONE ds_write_b64
// into P[q][k] (pitch 72: bank-floor for b64 writes and b128 reads). PV via K=32 MFMA.
__global__ __launch_bounds__(256) void attn_kernel(
        const unsigned short* __restrict__ qb,
        const unsigned short* __restrict__ kb,
        const unsigned short* __restrict__ vtb,
        unsigned short* __restrict__ attnb) {
    __shared__ union {
        unsigned short p[4][64][72];   // per-wave P tile (36.9 KB), pitch 72
        float c[2][64][66];            // combine buffers — used after barrier
    } sm;

    const f32x4 ZERO4 = {0.f, 0.f, 0.f, 0.f};
    int w = threadIdx.x >> 6;
    int lane = threadIdx.x & 63;
    int lrow = lane & 15, quad = lane >> 4;
    int bh = blockIdx.x & 15;
    int pr = blockIdx.x >> 4;                    // 0..31
    int bi = bh >> 3, h = bh & 7;

    const unsigned short* qh = qb + (size_t)bh * TT * HD;
    const unsigned short* kh = kb + (size_t)bh * TT * HD;
    const unsigned short* vth = vtb + (size_t)bh * HD * TT;
    bf16x8 ones = ones_frag();

    for (int half = 0; half < 2; half++) {
        int qt = half ? (63 - pr) : pr;
        int q0 = qt * 64;

        // Q fragments (serve as MFMA B operand in S^T = K·Q^T)
        bf16x8 qB[4][2];
        #pragma unroll
        for (int qf = 0; qf < 4; qf++) {
            const unsigned short* qp = qh + (q0 + qf * 16 + lrow) * HD + quad * 8;
            qB[qf][0] = load8(qp);
            qB[qf][1] = load8(qp + 32);
        }

        f32x4 o[4][4];
        f32x4 l[4];
        #pragma unroll
        for (int i = 0; i < 4; i++) {
            l[i] = ZERO4;
            #pragma unroll
            for (int j = 0; j < 4; j++) o[i][j] = ZERO4;
        }

        for (int kt = w; kt <= qt; kt += 4) {
            int kbase = kt * 64;
            bool diag = (kt == qt);
            bf16x8 kf[4][2], vf[4][2];
            #pragma unroll
            for (int nf = 0; nf < 4; nf++) {
                const unsigned short* kp = kh + (kbase + nf * 16 + lrow) * HD + quad * 8;
                kf[nf][0] = load8(kp);
                kf[nf][1] = load8(kp + 32);
                const unsigned short* vp = vth + (nf * 16 + lrow) * TT + kbase + quad * 8;
                vf[nf][0] = load8(vp);
                vf[nf][1] = load8(vp + 32);
            }
            // qf-pipelined: write P rows for qf, then immediately PV that row-block
            #pragma unroll
            for (int qf = 0; qf < 4; qf++) {
                #pragma unroll
                for (int tf = 0; tf < 4; tf++) {
                    unsigned d01[2];
                    if (diag && tf > qf) {           // fully-masked sub-tile
                        d01[0] = 0u; d01[1] = 0u;
                    } else {
                        f32x4 s = MFMA32(kf[tf][0], qB[qf][0], ZERO4);
                        s = MFMA32(kf[tf][1], qB[qf][1], s);
                        float p0 = __builtin_amdgcn_exp2f(s[0] * SCALE_L2E - SHIFT_L2E);
                        float p1 = __builtin_amdgcn_exp2f(s[1] * SCALE_L2E - SHIFT_L2E);
                        float p2 = __builtin_amdgcn_exp2f(s[2] * SCALE_L2E - SHIFT_L2E);
                        float p3 = __builtin_amdgcn_exp2f(s[3] * SCALE_L2E - SHIFT_L2E);
                        if (diag && tf == qf) {      // element mask: k > q
                            if (quad * 4 + 0 > lrow) p0 = 0.f;
                            if (quad * 4 + 1 > lrow) p1 = 0.f;
                            if (quad * 4 + 2 > lrow) p2 = 0.f;
                            if (quad * 4 + 3 > lrow) p3 = 0.f;
                        }
                        d01[0] = bfpack2_t(p0, p1);
                        d01[1] = bfpack2_t(p2, p3);
                    }
                    __builtin_memcpy(&sm.p[w][qf * 16 + lrow][tf * 16 + quad * 4], d01, 8);
                }
                bf16x8 pa0, pa1;
                __builtin_memcpy(&pa0, &sm.p[w][qf * 16 + lrow][quad * 8], 16);
                __builtin_memcpy(&pa1, &sm.p[w][qf * 16 + lrow][32 + quad * 8], 16);
                l[qf] = MFMA32(pa0, ones, l[qf]);
                l[qf] = MFMA32(pa1, ones, l[qf]);
                #pragma unroll
                for (int nfd = 0; nfd < 4; nfd++) {
                    o[qf][nfd] = MFMA32(pa0, vf[nfd][0], o[qf][nfd]);
                    o[qf][nfd] = MFMA32(pa1, vf[nfd][1], o[qf][nfd]);
                }
            }
        }

        // -------- combine 4 waves' partials (pure sums) --------
        __syncthreads();                       // all waves done with P tiles
        if (w >= 2) {                          // round 1: waves 2,3 -> bufs 0,1
            int cb = w - 2;
            #pragma unroll
            for (int mf = 0; mf < 4; mf++)
                #pragma unroll
                for (int r = 0; r < 4; r++) {
                    int row = mf * 16 + quad * 4 + r;
                    #pragma unroll
                    for (int nfd = 0; nfd < 4; nfd++)
                        sm.c[cb][row][nfd * 16 + lrow] = o[mf][nfd][r];
                    if (lrow == 0) sm.c[cb][row][64] = l[mf][r];
                }
        }
        __syncthreads();
        if (w < 2) {                           // round 2: waves 0,1 add
            #pragma unroll
            for (int mf = 0; mf < 4; mf++)
                #pragma unroll
                for (int r = 0; r < 4; r++) {
                    int row = mf * 16 + quad * 4 + r;
                    #pragma unroll
                    for (int nfd = 0; nfd < 4; nfd++)
                        sm.c[w][row][nfd * 16 + lrow] += o[mf][nfd][r];
                    if (lrow == 0) sm.c[w][row][64] += l[mf][r];
                }
        }
        __syncthreads();
        // round 3: every thread normalizes + stores one (row, 16-col) slice
        {
            int q = threadIdx.x >> 2, dseg = (threadIdx.x & 3) * 16;
            const float* r0 = &sm.c[0][q][0];
            const float* r1 = &sm.c[1][q][0];
            float inv = 1.0f / (r0[64] + r1[64]);
            unsigned outp[8];
            #pragma unroll
            for (int i = 0; i < 8; i++) {
                float a0 = (r0[dseg + 2 * i] + r1[dseg + 2 * i]) * inv;
                float a1 = (r0[dseg + 2 * i + 1] + r1[dseg + 2 * i + 1]) * inv;
                outp[i] = (unsigned)f2bf_t(a0) | ((unsigned)f2bf_t(a1) << 16);
            }
            unsigned short* dst = attnb + ((size_t)(bi * TT + q0 + q)) * DD + h * HD + dseg;
            __builtin_memcpy(dst, outp, 16);
            __builtin_memcpy(dst + 8, outp + 4, 16);
        }
        __syncthreads();                       // before next half reuses sm
    }
}

// ---------------- out projection: [8192,512]bf16 x [512,512]^T fp32 -> fp32 ----------------
// 64x128 block tiles (512 blocks); fused wout cast; swizzled staging
__global__ __launch_bounds__(256) void proj_gemm(
        const unsigned short* __restrict__ ab,
        const float* __restrict__ wout,
        float* __restrict__ out) {
    __shared__ struct { unsigned short As[64 * 32]; unsigned short Bs[128 * 32]; } sm;
    int tid = threadIdx.x;
    int w = tid >> 6, lane = tid & 63;
    int lrow = lane & 15, quad = lane >> 4;
    int bn = blockIdx.x % (DD / 128);         // 4
    int bm = blockIdx.x / (DD / 128);         // 128
    int m0 = bm * 64, n0 = bn * 128;
    int arow = tid >> 2, aseg = tid & 3;      // A staging: 64 rows x 4 chunks
    int ac = (aseg + ((arow >> 1) & 3)) & 3;
    int brow = tid >> 1, bhalf = tid & 1;     // B staging: 128 rows x 2 halves
    int brs = (brow >> 1) & 3;
    int bc0 = (2 * bhalf + brs) & 3, bc1 = (2 * bhalf + 1 + brs) & 3;
    int rs = (lrow >> 1) & 3;

    f32x4 c[4][2];
    #pragma unroll
    for (int i = 0; i < 4; i++)
        #pragma unroll
        for (int j = 0; j < 2; j++) c[i][j] = (f32x4){0.f, 0.f, 0.f, 0.f};

    for (int k0 = 0; k0 < DD; k0 += 32) {
        unsigned short apx[8];
        __builtin_memcpy(apx, ab + (size_t)(m0 + arow) * DD + k0 + aseg * 8, 16);
        const float4* bx = (const float4*)(wout + (size_t)(n0 + brow) * DD + k0 + bhalf * 16);
        float4 b0 = bx[0], b1 = bx[1], b2 = bx[2], b3 = bx[3];
        unsigned bp[8];
        pack16(b0, b1, b2, b3, bp);
        __builtin_memcpy(&sm.As[arow * 32 + ac * 8], apx, 16);
        __builtin_memcpy(&sm.Bs[brow * 32 + bc0 * 8], &bp[0], 16);
        __builtin_memcpy(&sm.Bs[brow * 32 + bc1 * 8], &bp[4], 16);
        __syncthreads();
        bf16x8 a[4], b[2];
        #pragma unroll
        for (int mf = 0; mf < 4; mf++)
            a[mf] = load8(&sm.As[(mf * 16 + lrow) * 32 + ((quad + rs) & 3) * 8]);
        #pragma unroll
        for (int nf = 0; nf < 2; nf++)
            b[nf] = load8(&sm.Bs[(w * 32 + nf * 16 + lrow) * 32 + ((quad + rs) & 3) * 8]);
        #pragma unroll
        for (int mf = 0; mf < 4; mf++)
            #pragma unroll
            for (int nf = 0; nf < 2; nf++)
                c[mf][nf] = MFMA32(a[mf], b[nf], c[mf][nf]);
        __syncthreads();
    }

    #pragma unroll
    for (int mf = 0; mf < 4; mf++) {
        #pragma unroll
        for (int r = 0; r < 4; r++) {
            int m = m0 + mf * 16 + quad * 4 + r;
            #pragma unroll
            for (int nf = 0; nf < 2; nf++) {
                int n = n0 + w * 32 + nf * 16 + lrow;
                out[(size_t)m * DD + n] = c[mf][nf][r];
            }
        }
    }
}

extern "C" void kernel_launch(void* const* d_in, const int* in_sizes, int n_in,
                              void* d_out, int out_size, void* d_ws, size_t ws_size,
                              hipStream_t stream) {
    const float* x    = (const float*)d_in[0];   // [2,4096,512]
    const float* wqkv = (const float*)d_in[1];   // [1536,512]
    const float* wout = (const float*)d_in[2];   // [512,512]
    float* out = (float*)d_out;                  // [2,4096,512]

    char* ws = (char*)d_ws;
    unsigned short* qb    = (unsigned short*)ws; ws += (size_t)BB * HH * TT * HD * 2;
    unsigned short* kb    = (unsigned short*)ws; ws += (size_t)BB * HH * TT * HD * 2;
    unsigned short* vtb   = (unsigned short*)ws; ws += (size_t)BB * HH * HD * TT * 2;
    unsigned short* attnb = (unsigned short*)ws; ws += (size_t)M_TOT * DD * 2;

    // fused cast: qkv reads fp32 directly (no cast kernel)
    qkv_gemm<<<(M_TOT / 128) * (N_QKV / 128), 256, 0, stream>>>(x, wqkv, qb, kb, vtb);

    // 16 bh x 32 pairs = 512 equal blocks (65 kt-units each), 4 waves
    attn_kernel<<<512, 256, 0, stream>>>(qb, kb, vtb, attnb);

    proj_gemm<<<(M_TOT / 64) * (DD / 128), 256, 0, stream>>>(attnb, wout, out);
}